// Round 3
// baseline (531.565 us; speedup 1.0000x reference)
//
#include <hip/hip_runtime.h>
#include <math.h>

#define NREG 90
#define NN 91
#define STR 92            // padded LDS row stride (floats), 16B-aligned rows
#define NPAIR 4005
#define H1 256
#define H2 256
#define F1 128

__global__ __launch_bounds__(256, 3)   // 3 blocks/CU -> VGPR cap ~170; w0..w90 must stay resident
void gcn_fused(const float* __restrict__ coh,   // [B, 4005]
               const float* __restrict__ W1,    // [256, 91]
               const float* __restrict__ W2,    // [256, 256]
               const float* __restrict__ Wo1,   // [128, 256]
               const float* __restrict__ bo1,   // [128]
               const float* __restrict__ Wo2,   // [2, 128]
               const float* __restrict__ bo2,   // [2]
               float* __restrict__ out)         // [B, 2]
{
    __shared__ __align__(16) float A[NN * STR];   // 33488 B
    __shared__ float dinv[NN];
    __shared__ __align__(16) float svec[H1];
    __shared__ __align__(16) float pooled[H2];
    __shared__ __align__(16) float fc1[F1];

    const int b = blockIdx.x;
    const int t = threadIdx.x;
    const float* cb = coh + (size_t)b * NPAIR;

    // ---- 1) zero A ----
    for (int i = t; i < NN * STR; i += 256) A[i] = 0.0f;
    __syncthreads();

    // ---- 2) scatter coh into strict upper triangle + mirror ----
    for (int m = t; m < NPAIR; m += 256) {
        float disc = 32041.0f - 8.0f * (float)m;        // 179^2 - 8m
        int i = (int)floorf((179.0f - sqrtf(disc)) * 0.5f);
        if (i < 0) i = 0;
        while (i > 0 && m < i * (179 - i) / 2) --i;
        while (m >= (i + 1) * (178 - i) / 2) ++i;
        int oi = i * (179 - i) / 2;
        int j = i + 1 + (m - oi);
        float v = cb[m];
        A[i * STR + j] = v;
        A[j * STR + i] = v;
    }
    __syncthreads();

    // ---- 3) supernode links + identity ----
    if (t < NN) {
        A[t * STR + t] = 1.0f;
        if (t < NREG) {
            A[NREG * STR + t] = 1.0f;
            A[t * STR + NREG] = 1.0f;
        }
    }
    __syncthreads();

    // ---- 4) degree^-1/2 ----
    if (t < NN) {
        float sum = 0.0f;
        const float* row = &A[t * STR];
        for (int j = 0; j < NN; ++j) sum += row[j];
        dinv[t] = 1.0f / sqrtf(sum);
    }
    __syncthreads();

    // ---- 5) A_hat = dinv[i] * A * dinv[j], in place ----
    for (int m = t; m < NN * NN; m += 256) {
        int i = m / NN;
        int j = m - i * NN;
        A[i * STR + j] *= dinv[i] * dinv[j];
    }
    __syncthreads();

    // ---- 6) W1 row -> 91 NAMED scalars (thread t owns channel h = t) ----
    // Named SSA values cannot fail SROA the way float w[91] did (VGPR stuck at 64).
    const float* w1r = W1 + t * NN;
#define LDW(i) const float w##i = w1r[i];
    LDW(0) LDW(1) LDW(2) LDW(3) LDW(4) LDW(5) LDW(6) LDW(7) LDW(8) LDW(9)
    LDW(10) LDW(11) LDW(12) LDW(13) LDW(14) LDW(15) LDW(16) LDW(17) LDW(18) LDW(19)
    LDW(20) LDW(21) LDW(22) LDW(23) LDW(24) LDW(25) LDW(26) LDW(27) LDW(28) LDW(29)
    LDW(30) LDW(31) LDW(32) LDW(33) LDW(34) LDW(35) LDW(36) LDW(37) LDW(38) LDW(39)
    LDW(40) LDW(41) LDW(42) LDW(43) LDW(44) LDW(45) LDW(46) LDW(47) LDW(48) LDW(49)
    LDW(50) LDW(51) LDW(52) LDW(53) LDW(54) LDW(55) LDW(56) LDW(57) LDW(58) LDW(59)
    LDW(60) LDW(61) LDW(62) LDW(63) LDW(64) LDW(65) LDW(66) LDW(67) LDW(68) LDW(69)
    LDW(70) LDW(71) LDW(72) LDW(73) LDW(74) LDW(75) LDW(76) LDW(77) LDW(78) LDW(79)
    LDW(80) LDW(81) LDW(82) LDW(83) LDW(84) LDW(85) LDW(86) LDW(87) LDW(88) LDW(89)
    LDW(90)
#undef LDW

    // ---- 7) main loop: s[h] = sum_j Ahat[90,j] * relu(dot(Ahat[j,:], w)) ----
    float acc = 0.0f;
    const float* arow = &A[NREG * STR];
    for (int j = 0; j < NN; ++j) {
        const float4* Aj4 = (const float4*)(&A[j * STR]);   // broadcast reads, conflict-free
        const float*  Aj  = &A[j * STR];
        float y0 = 0.0f, y1 = 0.0f, y2 = 0.0f, y3 = 0.0f;
#define STEP(q, a0, a1, a2, a3) { float4 av = Aj4[q]; \
        y0 = fmaf(av.x, a0, y0); y1 = fmaf(av.y, a1, y1); \
        y2 = fmaf(av.z, a2, y2); y3 = fmaf(av.w, a3, y3); }
        STEP(0,  w0,  w1,  w2,  w3)
        STEP(1,  w4,  w5,  w6,  w7)
        STEP(2,  w8,  w9,  w10, w11)
        STEP(3,  w12, w13, w14, w15)
        STEP(4,  w16, w17, w18, w19)
        STEP(5,  w20, w21, w22, w23)
        STEP(6,  w24, w25, w26, w27)
        STEP(7,  w28, w29, w30, w31)
        STEP(8,  w32, w33, w34, w35)
        STEP(9,  w36, w37, w38, w39)
        STEP(10, w40, w41, w42, w43)
        STEP(11, w44, w45, w46, w47)
        STEP(12, w48, w49, w50, w51)
        STEP(13, w52, w53, w54, w55)
        STEP(14, w56, w57, w58, w59)
        STEP(15, w60, w61, w62, w63)
        STEP(16, w64, w65, w66, w67)
        STEP(17, w68, w69, w70, w71)
        STEP(18, w72, w73, w74, w75)
        STEP(19, w76, w77, w78, w79)
        STEP(20, w80, w81, w82, w83)
        STEP(21, w84, w85, w86, w87)
#undef STEP
        y0 = fmaf(Aj[88], w88, y0);
        y1 = fmaf(Aj[89], w89, y1);
        y2 = fmaf(Aj[90], w90, y2);
        float y = (y0 + y1) + (y2 + y3);
        acc = fmaf(fmaxf(y, 0.0f), arow[j], acc);
    }

    svec[t] = acc;
    __syncthreads();

    // ---- 8) pooled[g] = sum_h W2[g,h] * s[h] ----
    {
        const float* w2r = W2 + t * H1;
        float p0 = 0.0f, p1 = 0.0f, p2 = 0.0f, p3 = 0.0f;
        #pragma unroll 8
        for (int q = 0; q < H1 / 4; ++q) {
            float4 sv = ((const float4*)svec)[q];
            float4 wv = ((const float4*)w2r)[q];
            p0 = fmaf(sv.x, wv.x, p0);
            p1 = fmaf(sv.y, wv.y, p1);
            p2 = fmaf(sv.z, wv.z, p2);
            p3 = fmaf(sv.w, wv.w, p3);
        }
        pooled[t] = (p0 + p1) + (p2 + p3);
    }
    __syncthreads();

    // ---- 9) fc1 = relu(Wo1 @ pooled + bo1) ----
    if (t < F1) {
        const float* wo1r = Wo1 + t * H2;
        float p0 = bo1[t], p1 = 0.0f, p2 = 0.0f, p3 = 0.0f;
        #pragma unroll 8
        for (int q = 0; q < H2 / 4; ++q) {
            float4 pv = ((const float4*)pooled)[q];
            float4 wv = ((const float4*)wo1r)[q];
            p0 = fmaf(pv.x, wv.x, p0);
            p1 = fmaf(pv.y, wv.y, p1);
            p2 = fmaf(pv.z, wv.z, p2);
            p3 = fmaf(pv.w, wv.w, p3);
        }
        fc1[t] = fmaxf((p0 + p1) + (p2 + p3), 0.0f);
    }
    __syncthreads();

    // ---- 10) out = Wo2 @ fc1 + bo2 ----
    if (t < 2) {
        const float* wo2r = Wo2 + t * F1;
        float p = bo2[t];
        for (int f = 0; f < F1; ++f) p = fmaf(wo2r[f], fc1[f], p);
        out[(size_t)b * 2 + t] = p;
    }
}

extern "C" void kernel_launch(void* const* d_in, const int* in_sizes, int n_in,
                              void* d_out, int out_size, void* d_ws, size_t ws_size,
                              hipStream_t stream) {
    const float* coh = (const float*)d_in[0];
    const float* W1  = (const float*)d_in[1];
    const float* W2  = (const float*)d_in[2];
    const float* Wo1 = (const float*)d_in[3];
    const float* bo1 = (const float*)d_in[4];
    const float* Wo2 = (const float*)d_in[5];
    const float* bo2 = (const float*)d_in[6];
    float* outp = (float*)d_out;

    const int B = in_sizes[0] / NPAIR;   // 4096
    gcn_fused<<<B, 256, 0, stream>>>(coh, W1, W2, Wo1, bo1, Wo2, bo2, outp);
}

// Round 4
// 529.618 us; speedup vs baseline: 1.0037x; 1.0037x over previous
//
#include <hip/hip_runtime.h>
#include <math.h>

#define NREG 90
#define NN 91
#define STR 92            // padded LDS row stride (floats), 16B-aligned rows
#define NPAIR 4005
#define H1 256
#define H2 256
#define F1 128

// waves_per_eu(2,4): cap the scheduler's occupancy TARGET at 4 waves/EU so the
// register-pressure budget is 2048/4=512 VGPR/wave -> the 91 W1 values stay
// register-resident. (launch_bounds' 2nd arg only sets the MIN; target stayed 8
// -> 64-VGPR budget -> W1 reloaded from cache every j-iter = 600us VMEM-bound.)
__global__ __launch_bounds__(256) __attribute__((amdgpu_waves_per_eu(2, 4)))
void gcn_fused(const float* __restrict__ coh,   // [B, 4005]
               const float* __restrict__ W1,    // [256, 91]
               const float* __restrict__ W2,    // [256, 256]
               const float* __restrict__ Wo1,   // [128, 256]
               const float* __restrict__ bo1,   // [128]
               const float* __restrict__ Wo2,   // [2, 128]
               const float* __restrict__ bo2,   // [2]
               float* __restrict__ out)         // [B, 2]
{
    __shared__ __align__(16) float A[NN * STR];   // 33488 B
    __shared__ float dinv[NN];
    __shared__ __align__(16) float svec[H1];
    __shared__ __align__(16) float pooled[H2];
    __shared__ __align__(16) float fc1[F1];

    const int b = blockIdx.x;
    const int t = threadIdx.x;
    const float* cb = coh + (size_t)b * NPAIR;

    // ---- 1) zero A ----
    for (int i = t; i < NN * STR; i += 256) A[i] = 0.0f;
    __syncthreads();

    // ---- 2) scatter coh into strict upper triangle + mirror ----
    for (int m = t; m < NPAIR; m += 256) {
        float disc = 32041.0f - 8.0f * (float)m;        // 179^2 - 8m
        int i = (int)floorf((179.0f - sqrtf(disc)) * 0.5f);
        if (i < 0) i = 0;
        while (i > 0 && m < i * (179 - i) / 2) --i;
        while (m >= (i + 1) * (178 - i) / 2) ++i;
        int oi = i * (179 - i) / 2;
        int j = i + 1 + (m - oi);
        float v = cb[m];
        A[i * STR + j] = v;
        A[j * STR + i] = v;
    }
    __syncthreads();

    // ---- 3) supernode links + identity ----
    if (t < NN) {
        A[t * STR + t] = 1.0f;
        if (t < NREG) {
            A[NREG * STR + t] = 1.0f;
            A[t * STR + NREG] = 1.0f;
        }
    }
    __syncthreads();

    // ---- 4) degree^-1/2 ----
    if (t < NN) {
        float sum = 0.0f;
        const float* row = &A[t * STR];
        for (int j = 0; j < NN; ++j) sum += row[j];
        dinv[t] = 1.0f / sqrtf(sum);
    }
    __syncthreads();

    // ---- 5) A_hat = dinv[i] * A * dinv[j], in place ----
    for (int m = t; m < NN * NN; m += 256) {
        int i = m / NN;
        int j = m - i * NN;
        A[i * STR + j] *= dinv[i] * dinv[j];
    }
    __syncthreads();

    // ---- 6) W1 row -> 91 named scalars, PINNED so loads can't sink into loop ----
    const float* w1r = W1 + t * NN;
#define LDW(i) float w##i = w1r[i];
    LDW(0) LDW(1) LDW(2) LDW(3) LDW(4) LDW(5) LDW(6) LDW(7) LDW(8) LDW(9)
    LDW(10) LDW(11) LDW(12) LDW(13) LDW(14) LDW(15) LDW(16) LDW(17) LDW(18) LDW(19)
    LDW(20) LDW(21) LDW(22) LDW(23) LDW(24) LDW(25) LDW(26) LDW(27) LDW(28) LDW(29)
    LDW(30) LDW(31) LDW(32) LDW(33) LDW(34) LDW(35) LDW(36) LDW(37) LDW(38) LDW(39)
    LDW(40) LDW(41) LDW(42) LDW(43) LDW(44) LDW(45) LDW(46) LDW(47) LDW(48) LDW(49)
    LDW(50) LDW(51) LDW(52) LDW(53) LDW(54) LDW(55) LDW(56) LDW(57) LDW(58) LDW(59)
    LDW(60) LDW(61) LDW(62) LDW(63) LDW(64) LDW(65) LDW(66) LDW(67) LDW(68) LDW(69)
    LDW(70) LDW(71) LDW(72) LDW(73) LDW(74) LDW(75) LDW(76) LDW(77) LDW(78) LDW(79)
    LDW(80) LDW(81) LDW(82) LDW(83) LDW(84) LDW(85) LDW(86) LDW(87) LDW(88) LDW(89)
    LDW(90)
#undef LDW
    // volatile asm pins: cannot be sunk into the loop or duplicated -> the
    // values feeding the loop are asm results, not rematerializable loads.
#define PIN(i) asm volatile("" : "+v"(w##i));
    PIN(0) PIN(1) PIN(2) PIN(3) PIN(4) PIN(5) PIN(6) PIN(7) PIN(8) PIN(9)
    PIN(10) PIN(11) PIN(12) PIN(13) PIN(14) PIN(15) PIN(16) PIN(17) PIN(18) PIN(19)
    PIN(20) PIN(21) PIN(22) PIN(23) PIN(24) PIN(25) PIN(26) PIN(27) PIN(28) PIN(29)
    PIN(30) PIN(31) PIN(32) PIN(33) PIN(34) PIN(35) PIN(36) PIN(37) PIN(38) PIN(39)
    PIN(40) PIN(41) PIN(42) PIN(43) PIN(44) PIN(45) PIN(46) PIN(47) PIN(48) PIN(49)
    PIN(50) PIN(51) PIN(52) PIN(53) PIN(54) PIN(55) PIN(56) PIN(57) PIN(58) PIN(59)
    PIN(60) PIN(61) PIN(62) PIN(63) PIN(64) PIN(65) PIN(66) PIN(67) PIN(68) PIN(69)
    PIN(70) PIN(71) PIN(72) PIN(73) PIN(74) PIN(75) PIN(76) PIN(77) PIN(78) PIN(79)
    PIN(80) PIN(81) PIN(82) PIN(83) PIN(84) PIN(85) PIN(86) PIN(87) PIN(88) PIN(89)
    PIN(90)
#undef PIN

    // ---- 7) main loop: s[h] = sum_j Ahat[90,j] * relu(dot(Ahat[j,:], w)) ----
    float acc = 0.0f;
    const float* arow = &A[NREG * STR];
    for (int j = 0; j < NN; ++j) {
        const float4* Aj4 = (const float4*)(&A[j * STR]);   // uniform-address broadcast reads
        const float*  Aj  = &A[j * STR];
        float y0 = 0.0f, y1 = 0.0f, y2 = 0.0f, y3 = 0.0f;
#define STEP(q, a0, a1, a2, a3) { float4 av = Aj4[q]; \
        y0 = fmaf(av.x, a0, y0); y1 = fmaf(av.y, a1, y1); \
        y2 = fmaf(av.z, a2, y2); y3 = fmaf(av.w, a3, y3); }
        STEP(0,  w0,  w1,  w2,  w3)
        STEP(1,  w4,  w5,  w6,  w7)
        STEP(2,  w8,  w9,  w10, w11)
        STEP(3,  w12, w13, w14, w15)
        STEP(4,  w16, w17, w18, w19)
        STEP(5,  w20, w21, w22, w23)
        STEP(6,  w24, w25, w26, w27)
        STEP(7,  w28, w29, w30, w31)
        STEP(8,  w32, w33, w34, w35)
        STEP(9,  w36, w37, w38, w39)
        STEP(10, w40, w41, w42, w43)
        STEP(11, w44, w45, w46, w47)
        STEP(12, w48, w49, w50, w51)
        STEP(13, w52, w53, w54, w55)
        STEP(14, w56, w57, w58, w59)
        STEP(15, w60, w61, w62, w63)
        STEP(16, w64, w65, w66, w67)
        STEP(17, w68, w69, w70, w71)
        STEP(18, w72, w73, w74, w75)
        STEP(19, w76, w77, w78, w79)
        STEP(20, w80, w81, w82, w83)
        STEP(21, w84, w85, w86, w87)
#undef STEP
        y0 = fmaf(Aj[88], w88, y0);
        y1 = fmaf(Aj[89], w89, y1);
        y2 = fmaf(Aj[90], w90, y2);
        float y = (y0 + y1) + (y2 + y3);
        acc = fmaf(fmaxf(y, 0.0f), arow[j], acc);
    }

    svec[t] = acc;
    __syncthreads();

    // ---- 8) pooled[g] = sum_h W2[g,h] * s[h] ----
    {
        const float* w2r = W2 + t * H1;
        float p0 = 0.0f, p1 = 0.0f, p2 = 0.0f, p3 = 0.0f;
        #pragma unroll 8
        for (int q = 0; q < H1 / 4; ++q) {
            float4 sv = ((const float4*)svec)[q];
            float4 wv = ((const float4*)w2r)[q];
            p0 = fmaf(sv.x, wv.x, p0);
            p1 = fmaf(sv.y, wv.y, p1);
            p2 = fmaf(sv.z, wv.z, p2);
            p3 = fmaf(sv.w, wv.w, p3);
        }
        pooled[t] = (p0 + p1) + (p2 + p3);
    }
    __syncthreads();

    // ---- 9) fc1 = relu(Wo1 @ pooled + bo1) ----
    if (t < F1) {
        const float* wo1r = Wo1 + t * H2;
        float p0 = bo1[t], p1 = 0.0f, p2 = 0.0f, p3 = 0.0f;
        #pragma unroll 8
        for (int q = 0; q < H2 / 4; ++q) {
            float4 pv = ((const float4*)pooled)[q];
            float4 wv = ((const float4*)wo1r)[q];
            p0 = fmaf(pv.x, wv.x, p0);
            p1 = fmaf(pv.y, wv.y, p1);
            p2 = fmaf(pv.z, wv.z, p2);
            p3 = fmaf(pv.w, wv.w, p3);
        }
        fc1[t] = fmaxf((p0 + p1) + (p2 + p3), 0.0f);
    }
    __syncthreads();

    // ---- 10) out = Wo2 @ fc1 + bo2 ----
    if (t < 2) {
        const float* wo2r = Wo2 + t * F1;
        float p = bo2[t];
        for (int f = 0; f < F1; ++f) p = fmaf(wo2r[f], fc1[f], p);
        out[(size_t)b * 2 + t] = p;
    }
}

extern "C" void kernel_launch(void* const* d_in, const int* in_sizes, int n_in,
                              void* d_out, int out_size, void* d_ws, size_t ws_size,
                              hipStream_t stream) {
    const float* coh = (const float*)d_in[0];
    const float* W1  = (const float*)d_in[1];
    const float* W2  = (const float*)d_in[2];
    const float* Wo1 = (const float*)d_in[3];
    const float* bo1 = (const float*)d_in[4];
    const float* Wo2 = (const float*)d_in[5];
    const float* bo2 = (const float*)d_in[6];
    float* outp = (float*)d_out;

    const int B = in_sizes[0] / NPAIR;   // 4096
    gcn_fused<<<B, 256, 0, stream>>>(coh, W1, W2, Wo1, bo1, Wo2, bo2, outp);
}

// Round 5
// 463.406 us; speedup vs baseline: 1.1471x; 1.1429x over previous
//
#include <hip/hip_runtime.h>
#include <math.h>

#define NREG 90
#define NN 91
#define JROWS 96          // j padded to 96 (rows 91..95 zero)
#define STR 92            // A row stride in floats (368 B, 16B-aligned)
#define NPAIR 4005
#define H1 256
#define H2 256
#define F1 128

// ---- pre-kernel: W1 [256][91] -> W1T [92][256] in workspace (row 91 zeroed) ----
__global__ void transpose_w1(const float* __restrict__ W1, float* __restrict__ W1T) {
    int k = blockIdx.x;          // 0..91
    int h = threadIdx.x;         // 0..255
    W1T[k * 256 + h] = (k < NN) ? W1[h * NN + k] : 0.0f;
}

__global__ __launch_bounds__(256)
void gcn_fused(const float* __restrict__ coh,   // [B, 4005]
               const float* __restrict__ W1T,   // [92, 256] (workspace)
               const float* __restrict__ W2,    // [256, 256]
               const float* __restrict__ Wo1,   // [128, 256]
               const float* __restrict__ bo1,   // [128]
               const float* __restrict__ Wo2,   // [2, 128]
               const float* __restrict__ bo2,   // [2]
               float* __restrict__ out)         // [B, 2]
{
    __shared__ __align__(16) float A[JROWS * STR];   // 35328 B
    __shared__ __align__(16) float Wl[92 * 64];      // 23552 B, one 64-col quarter of W1T
    __shared__ __align__(16) float part[16 * 64];    // 4096 B, ty-partials
    __shared__ __align__(16) float svec[H1];
    __shared__ __align__(16) float pooled[H2];
    __shared__ __align__(16) float fc1[F1];
    __shared__ float dinv[NN];

    const int b = blockIdx.x;
    const int t = threadIdx.x;
    const float* cb = coh + (size_t)b * NPAIR;

    // ---- 1) zero A (incl. pad rows 91..95 and pad col 91) ----
    for (int i = t; i < JROWS * STR; i += 256) A[i] = 0.0f;
    __syncthreads();

    // ---- 2) scatter coh into strict upper triangle + mirror ----
    for (int m = t; m < NPAIR; m += 256) {
        float disc = 32041.0f - 8.0f * (float)m;        // 179^2 - 8m
        int i = (int)floorf((179.0f - sqrtf(disc)) * 0.5f);
        if (i < 0) i = 0;
        while (i > 0 && m < i * (179 - i) / 2) --i;
        while (m >= (i + 1) * (178 - i) / 2) ++i;
        int oi = i * (179 - i) / 2;
        int j = i + 1 + (m - oi);
        float v = cb[m];
        A[i * STR + j] = v;
        A[j * STR + i] = v;
    }
    __syncthreads();

    // ---- 3) supernode links + identity ----
    if (t < NN) {
        A[t * STR + t] = 1.0f;
        if (t < NREG) {
            A[NREG * STR + t] = 1.0f;
            A[t * STR + NREG] = 1.0f;
        }
    }
    __syncthreads();

    // ---- 4) degree^-1/2 ----
    if (t < NN) {
        float sum = 0.0f;
        const float* row = &A[t * STR];
        for (int j = 0; j < NN; ++j) sum += row[j];
        dinv[t] = 1.0f / sqrtf(sum);
    }
    __syncthreads();

    // ---- 5) A_hat = dinv[i] * A * dinv[j], in place ----
    for (int m = t; m < NN * NN; m += 256) {
        int i = m / NN;
        int j = m - i * NN;
        A[i * STR + j] *= dinv[i] * dinv[j];
    }

    // ---- 7) register-tiled: z[j][h] = dot(Ahat[j,:], W1T[:,h]); s[h] = sum_j arow[j]*relu(z) ----
    // 256 threads = 16 tx (4 h-cols each) x 16 ty (6 j-rows each). 4 quarters of 64 h-cols.
    const int tx = t & 15;
    const int ty = t >> 4;
    const int jb = ty * 6;
    const float* arow = &A[NREG * STR];

    for (int q = 0; q < 4; ++q) {
        __syncthreads();   // previous quarter's Wl/part readers done (q=0: A-build done)
        // stage Wl = W1T[0..91][q*64 .. q*64+63], coalesced b128 both sides
        for (int idx = t; idx < 92 * 16; idx += 256) {
            int row = idx >> 4;
            int c4  = (idx & 15) << 2;
            *(float4*)&Wl[row * 64 + c4] =
                *(const float4*)&W1T[row * 256 + q * 64 + c4];
        }
        __syncthreads();

        float acc[6][4] = {{0.f}};
        #pragma unroll 2
        for (int k = 0; k < 92; k += 2) {
            float4 w0 = *(const float4*)&Wl[k * 64 + tx * 4];        // 2-way bank alias: free
            float4 w1 = *(const float4*)&Wl[(k + 1) * 64 + tx * 4];
            #pragma unroll
            for (int r = 0; r < 6; ++r) {
                float2 av = *(const float2*)&A[(jb + r) * STR + k];  // 4 addrs/wave: free
                acc[r][0] = fmaf(av.y, w1.x, fmaf(av.x, w0.x, acc[r][0]));
                acc[r][1] = fmaf(av.y, w1.y, fmaf(av.x, w0.y, acc[r][1]));
                acc[r][2] = fmaf(av.y, w1.z, fmaf(av.x, w0.z, acc[r][2]));
                acc[r][3] = fmaf(av.y, w1.w, fmaf(av.x, w0.w, acc[r][3]));
            }
        }

        // epilogue: sp[c] = sum_r arow[j]*relu(acc[r][c])
        float sp0 = 0.f, sp1 = 0.f, sp2 = 0.f, sp3 = 0.f;
        #pragma unroll
        for (int r = 0; r < 6; ++r) {
            int j = jb + r;
            float aj = (j <= NREG) ? arow[j] : 0.0f;   // pad rows contribute 0
            sp0 = fmaf(aj, fmaxf(acc[r][0], 0.f), sp0);
            sp1 = fmaf(aj, fmaxf(acc[r][1], 0.f), sp1);
            sp2 = fmaf(aj, fmaxf(acc[r][2], 0.f), sp2);
            sp3 = fmaf(aj, fmaxf(acc[r][3], 0.f), sp3);
        }
        *(float4*)&part[ty * 64 + tx * 4] = make_float4(sp0, sp1, sp2, sp3);
        __syncthreads();
        if (t < 64) {
            float s = 0.f;
            #pragma unroll
            for (int i = 0; i < 16; ++i) s += part[i * 64 + t];
            svec[q * 64 + t] = s;
        }
    }
    __syncthreads();

    // ---- 8) pooled[g] = sum_h W2[g,h] * s[h] ----
    {
        const float* w2r = W2 + t * H1;
        float p0 = 0.f, p1 = 0.f, p2 = 0.f, p3 = 0.f;
        #pragma unroll 8
        for (int qq = 0; qq < H1 / 4; ++qq) {
            float4 sv = ((const float4*)svec)[qq];
            float4 wv = ((const float4*)w2r)[qq];
            p0 = fmaf(sv.x, wv.x, p0);
            p1 = fmaf(sv.y, wv.y, p1);
            p2 = fmaf(sv.z, wv.z, p2);
            p3 = fmaf(sv.w, wv.w, p3);
        }
        pooled[t] = (p0 + p1) + (p2 + p3);
    }
    __syncthreads();

    // ---- 9) fc1 = relu(Wo1 @ pooled + bo1) ----
    if (t < F1) {
        const float* wo1r = Wo1 + t * H2;
        float p0 = bo1[t], p1 = 0.f, p2 = 0.f, p3 = 0.f;
        #pragma unroll 8
        for (int qq = 0; qq < H2 / 4; ++qq) {
            float4 pv = ((const float4*)pooled)[qq];
            float4 wv = ((const float4*)wo1r)[qq];
            p0 = fmaf(pv.x, wv.x, p0);
            p1 = fmaf(pv.y, wv.y, p1);
            p2 = fmaf(pv.z, wv.z, p2);
            p3 = fmaf(pv.w, wv.w, p3);
        }
        fc1[t] = fmaxf((p0 + p1) + (p2 + p3), 0.f);
    }
    __syncthreads();

    // ---- 10) out = Wo2 @ fc1 + bo2 ----
    if (t < 2) {
        const float* wo2r = Wo2 + t * F1;
        float p = bo2[t];
        for (int f = 0; f < F1; ++f) p = fmaf(wo2r[f], fc1[f], p);
        out[(size_t)b * 2 + t] = p;
    }
}

extern "C" void kernel_launch(void* const* d_in, const int* in_sizes, int n_in,
                              void* d_out, int out_size, void* d_ws, size_t ws_size,
                              hipStream_t stream) {
    const float* coh = (const float*)d_in[0];
    const float* W1  = (const float*)d_in[1];
    const float* W2  = (const float*)d_in[2];
    const float* Wo1 = (const float*)d_in[3];
    const float* bo1 = (const float*)d_in[4];
    const float* Wo2 = (const float*)d_in[5];
    const float* bo2 = (const float*)d_in[6];
    float* outp = (float*)d_out;
    float* W1T  = (float*)d_ws;          // 92*256*4 = 94208 B

    const int B = in_sizes[0] / NPAIR;   // 4096
    transpose_w1<<<92, 256, 0, stream>>>(W1, W1T);
    gcn_fused<<<B, 256, 0, stream>>>(coh, W1T, W2, Wo1, bo1, Wo2, bo2, outp);
}

// Round 6
// 378.455 us; speedup vs baseline: 1.4046x; 1.2245x over previous
//
#include <hip/hip_runtime.h>
#include <math.h>

#define NREG 90
#define NN 91
#define JROWS 96          // j padded to 96 (rows 91..95 zero)
#define STR 92            // A row stride in floats (368 B, 16B-aligned)
#define NPAIR 4005
#define H1 256
#define H2 256
#define F1 128

// ---- one-shot prep: W1 [256][91] -> W1T [92][256] (row 91 zero) + pair table ----
__global__ void prep(const float* __restrict__ W1, float* __restrict__ W1T,
                     int* __restrict__ ptab) {
    int t = blockIdx.x * 256 + threadIdx.x;
    if (t < 92 * 256) {
        int k = t >> 8, h = t & 255;
        W1T[t] = (k < NN) ? W1[h * NN + k] : 0.0f;
    }
    if (t < NPAIR) {
        float disc = 32041.0f - 8.0f * (float)t;        // 179^2 - 8m
        int i = (int)floorf((179.0f - sqrtf(disc)) * 0.5f);
        if (i < 0) i = 0;
        while (i > 0 && t < i * (179 - i) / 2) --i;
        while (t >= (i + 1) * (178 - i) / 2) ++i;
        int j = i + 1 + (t - i * (179 - i) / 2);
        ptab[t] = (i << 7) | j;                          // i<=88, j<=89: 7 bits each
    }
}

__global__ __launch_bounds__(256)
void gcn_fused(const float* __restrict__ coh,   // [B, 4005]
               const float* __restrict__ W1T,   // [92, 256] (ws)
               const int*   __restrict__ ptab,  // [4005]    (ws)
               const float* __restrict__ W2,    // [256, 256]
               const float* __restrict__ Wo1,   // [128, 256]
               const float* __restrict__ bo1,   // [128]
               const float* __restrict__ Wo2,   // [2, 128]
               const float* __restrict__ bo2,   // [2]
               float* __restrict__ out)         // [B, 2]
{
    __shared__ __align__(16) float A[JROWS * STR];   // 35328 B
    __shared__ __align__(16) float part[4 * 64];     // 1024 B (cross-wave partials)
    __shared__ __align__(16) float svec[H1];
    __shared__ __align__(16) float pooled[H2];
    __shared__ __align__(16) float fc1[F1];
    __shared__ __align__(16) float dinv[JROWS];
    // total ~39.3 KB -> 4 blocks/CU

    const int b = blockIdx.x;
    const int t = threadIdx.x;
    const float* cb = coh + (size_t)b * NPAIR;

    // ---- 1) zero A (float4) ----
    for (int m = t; m < JROWS * STR / 4; m += 256)
        ((float4*)A)[m] = make_float4(0.f, 0.f, 0.f, 0.f);
    __syncthreads();

    // ---- 2) scatter (table-driven) + supernode + identity (disjoint -> one phase) ----
    for (int m = t; m < NPAIR; m += 256) {
        int p = ptab[m];
        int i = p >> 7, j = p & 127;
        float v = cb[m];
        A[i * STR + j] = v;
        A[j * STR + i] = v;
    }
    if (t < NN) {
        A[t * STR + t] = 1.0f;
        if (t < NREG) {
            A[NREG * STR + t] = 1.0f;
            A[t * STR + NREG] = 1.0f;
        }
    }
    __syncthreads();

    // ---- 3) degree^-1/2 (float4 row sum); pad rows get dinv=0 (keeps 0*0=0, no NaN) ----
    if (t < JROWS) {
        if (t < NN) {
            const float4* row = (const float4*)&A[t * STR];
            float sx = 0.f, sy = 0.f, sz = 0.f, sw = 0.f;
            #pragma unroll
            for (int q = 0; q < STR / 4; ++q) {
                float4 v = row[q];
                sx += v.x; sy += v.y; sz += v.z; sw += v.w;
            }
            dinv[t] = 1.0f / sqrtf((sx + sy) + (sz + sw));
        } else {
            dinv[t] = 0.0f;
        }
    }
    __syncthreads();

    // ---- 4) A_hat scale (float4; pad col 91 / rows 91+ stay 0) ----
    for (int m = t; m < JROWS * (STR / 4); m += 256) {
        int i = m / (STR / 4);
        int c4 = (m - i * (STR / 4)) * 4;
        float di = dinv[i];
        float4 dj = *(const float4*)&dinv[c4];
        float4 v = ((float4*)A)[m];
        v.x *= di * dj.x; v.y *= di * dj.y; v.z *= di * dj.z; v.w *= di * dj.w;
        ((float4*)A)[m] = v;
    }
    __syncthreads();

    // ---- 5) main: z[j][h]=dot(Ahat[j,:],W1T[:,h]); s[h]=sum_j arow[j]*relu(z) ----
    // 16 tx (4 cols) x 16 ty (6 rows). W read from global (L1/L2-resident quarter).
    const int tx = t & 15;
    const int ty = t >> 4;
    const int jb = ty * 6;
    const int wv = t >> 6;
    const float* arow = &A[NREG * STR];

    for (int q = 0; q < 4; ++q) {
        const float* Wq = W1T + q * 64 + tx * 4;
        float acc[6][4] = {{0.f}};
        #pragma unroll 2
        for (int k = 0; k < STR; k += 2) {
            float4 w0 = *(const float4*)(Wq + (size_t)k * 256);
            float4 w1 = *(const float4*)(Wq + (size_t)(k + 1) * 256);
            #pragma unroll
            for (int r = 0; r < 6; ++r) {
                float2 av = *(const float2*)&A[(jb + r) * STR + k];  // 4 addrs/wave: broadcast
                acc[r][0] = fmaf(av.y, w1.x, fmaf(av.x, w0.x, acc[r][0]));
                acc[r][1] = fmaf(av.y, w1.y, fmaf(av.x, w0.y, acc[r][1]));
                acc[r][2] = fmaf(av.y, w1.z, fmaf(av.x, w0.z, acc[r][2]));
                acc[r][3] = fmaf(av.y, w1.w, fmaf(av.x, w0.w, acc[r][3]));
            }
        }

        // epilogue: per-thread weighted-relu partial over its 6 rows
        float sp0 = 0.f, sp1 = 0.f, sp2 = 0.f, sp3 = 0.f;
        #pragma unroll
        for (int r = 0; r < 6; ++r) {
            int j = jb + r;
            float aj = (j <= NREG) ? arow[j] : 0.0f;
            sp0 = fmaf(aj, fmaxf(acc[r][0], 0.f), sp0);
            sp1 = fmaf(aj, fmaxf(acc[r][1], 0.f), sp1);
            sp2 = fmaf(aj, fmaxf(acc[r][2], 0.f), sp2);
            sp3 = fmaf(aj, fmaxf(acc[r][3], 0.f), sp3);
        }
        // in-wave reduce over ty-local (lane bits 4,5)
        sp0 += __shfl_xor(sp0, 16); sp1 += __shfl_xor(sp1, 16);
        sp2 += __shfl_xor(sp2, 16); sp3 += __shfl_xor(sp3, 16);
        sp0 += __shfl_xor(sp0, 32); sp1 += __shfl_xor(sp1, 32);
        sp2 += __shfl_xor(sp2, 32); sp3 += __shfl_xor(sp3, 32);
        if ((t & 63) < 16)
            *(float4*)&part[wv * 64 + tx * 4] = make_float4(sp0, sp1, sp2, sp3);
        __syncthreads();
        if (t < 64)
            svec[q * 64 + t] = (part[t] + part[64 + t]) + (part[128 + t] + part[192 + t]);
        __syncthreads();   // part safe to overwrite next quarter; svec ready at loop end
    }

    // ---- 6) pooled[g] = sum_h W2[g,h] * s[h] ----
    {
        const float* w2r = W2 + t * H1;
        float p0 = 0.f, p1 = 0.f, p2 = 0.f, p3 = 0.f;
        #pragma unroll 8
        for (int qq = 0; qq < H1 / 4; ++qq) {
            float4 sv = ((const float4*)svec)[qq];
            float4 wv4 = ((const float4*)w2r)[qq];
            p0 = fmaf(sv.x, wv4.x, p0);
            p1 = fmaf(sv.y, wv4.y, p1);
            p2 = fmaf(sv.z, wv4.z, p2);
            p3 = fmaf(sv.w, wv4.w, p3);
        }
        pooled[t] = (p0 + p1) + (p2 + p3);
    }
    __syncthreads();

    // ---- 7) fc1 = relu(Wo1 @ pooled + bo1) ----
    if (t < F1) {
        const float* wo1r = Wo1 + t * H2;
        float p0 = bo1[t], p1 = 0.f, p2 = 0.f, p3 = 0.f;
        #pragma unroll 8
        for (int qq = 0; qq < H2 / 4; ++qq) {
            float4 pv = ((const float4*)pooled)[qq];
            float4 wv4 = ((const float4*)wo1r)[qq];
            p0 = fmaf(pv.x, wv4.x, p0);
            p1 = fmaf(pv.y, wv4.y, p1);
            p2 = fmaf(pv.z, wv4.z, p2);
            p3 = fmaf(pv.w, wv4.w, p3);
        }
        fc1[t] = fmaxf((p0 + p1) + (p2 + p3), 0.f);
    }
    __syncthreads();

    // ---- 8) out = Wo2 @ fc1 + bo2 ----
    if (t < 2) {
        const float* wo2r = Wo2 + t * F1;
        float p = bo2[t];
        for (int f = 0; f < F1; ++f) p = fmaf(wo2r[f], fc1[f], p);
        out[(size_t)b * 2 + t] = p;
    }
}

extern "C" void kernel_launch(void* const* d_in, const int* in_sizes, int n_in,
                              void* d_out, int out_size, void* d_ws, size_t ws_size,
                              hipStream_t stream) {
    const float* coh = (const float*)d_in[0];
    const float* W1  = (const float*)d_in[1];
    const float* W2  = (const float*)d_in[2];
    const float* Wo1 = (const float*)d_in[3];
    const float* bo1 = (const float*)d_in[4];
    const float* Wo2 = (const float*)d_in[5];
    const float* bo2 = (const float*)d_in[6];
    float* outp = (float*)d_out;

    float* W1T = (float*)d_ws;                         // 92*256*4 = 94208 B
    int*   ptab = (int*)((char*)d_ws + 92 * 256 * 4);  // 4005*4 B

    const int B = in_sizes[0] / NPAIR;   // 4096
    prep<<<92, 256, 0, stream>>>(W1, W1T, ptab);
    gcn_fused<<<B, 256, 0, stream>>>(coh, W1T, ptab, W2, Wo1, bo1, Wo2, bo2, outp);
}